// Round 9
// baseline (688.203 us; speedup 1.0000x reference)
//
#include <hip/hip_runtime.h>

#define N_ROWS 16384
#define DDIM   256
#define VCODES 8192
#define BETA   0.25f
#define DELTA  0.02f   // rescore window; > 2x max approx error (~4e-3) w/ margin

using f16   = _Float16;
using f16x4 = __attribute__((ext_vector_type(4))) _Float16;
using f16x8 = __attribute__((ext_vector_type(8))) _Float16;
using f32x4 = __attribute__((ext_vector_type(4))) float;

typedef __attribute__((address_space(1))) const unsigned int gu32_t;
typedef __attribute__((address_space(3))) unsigned int       lu32_t;

__device__ __forceinline__ void gload16(const void* g, void* l) {
    __builtin_amdgcn_global_load_lds((gu32_t*)g, (lu32_t*)l, 16, 0, 0);
}

// ============================================================================
// Packed fragment-major layout (validated R2-R8), hi-only now:
//   array[rowtile16][ktile 0..7][512 f16]  (1 KB per 16-row x 32-col subtile)
//   element (r, c) at f16 index (c>>3)*128 + r*8 + (c&7) == lane*8+j fragment
//   order for mfma_f32_16x16x32_f16.
// ============================================================================

__global__ void split_lat(const float* __restrict__ lat, f16* __restrict__ Ap) {
    int t = blockIdx.x * 256 + threadIdx.x;
    float4 x = *(const float4*)&lat[(size_t)t * 4];
    int row = t >> 6;
    int c   = (t & 63) * 4;
    f16x4 hi = {(f16)x.x, (f16)x.y, (f16)x.z, (f16)x.w};
    int kt  = c >> 5;
    int sub = ((c & 31) >> 3) * 128 + (row & 15) * 8 + (c & 7);
    size_t base = ((size_t)(row >> 4) * 8);
    *(f16x4*)&Ap[(base + kt) * 512 + sub] = hi;
}

__global__ void split_cb(const float* __restrict__ cb, f16* __restrict__ Bp) {
    int t = blockIdx.x * 256 + threadIdx.x;
    float4 e = *(const float4*)&cb[(size_t)t * 4];
    // E = 64*e keeps f16 values normal; acc = 64*x.e, score = cbn - acc/32
    f16x4 hi = {(f16)(e.x * 64.0f), (f16)(e.y * 64.0f),
                (f16)(e.z * 64.0f), (f16)(e.w * 64.0f)};
    int row = t >> 6;
    int c   = (t & 63) * 4;
    int kt  = c >> 5;
    int sub = ((c & 31) >> 3) * 128 + (row & 15) * 8 + (c & 7);
    size_t base = ((size_t)(row >> 4) * 8);
    *(f16x4*)&Bp[(base + kt) * 512 + sub] = hi;
}

__global__ void cbnorm_k(const float* __restrict__ cb, float* __restrict__ cbnorm) {
    int gtid = blockIdx.x * blockDim.x + threadIdx.x;
    int wave = gtid >> 6;
    int lane = threadIdx.x & 63;
    if (wave >= VCODES) return;
    float4 v = *(const float4*)(cb + (size_t)wave * DDIM + lane * 4);
    float s = v.x * v.x + v.y * v.y + v.z * v.z + v.w * v.w;
    #pragma unroll
    for (int m = 32; m; m >>= 1) s += __shfl_xor(s, m, 64);
    if (lane == 0) cbnorm[wave] = s;
}

// ---------- lexicographic (score, idx) top-2 insert ----------
__device__ __forceinline__ void ins2(float v, int i,
                                     float& m1, int& i1, float& m2, int& i2) {
    if (v < m1 || (v == m1 && i < i1)) { m2 = m1; i2 = i1; m1 = v; i1 = i; }
    else if (v < m2 || (v == m2 && i < i2)) { m2 = v; i2 = i; }
}

// ---------- main: 256x256 tile, 8 waves (2Mx4N), 8 K-tiles, double buffer ---
// R7-proven sync: ONE __syncthreads per K-tile; stage(vk+1) issued right after
// the barrier into buf^1, drains at the NEXT __syncthreads.
// Epilogue: per-row TOP-2 over each wave's 64-code quarter (shuffle pair-merge),
// cross-wc merge via LDS scratch -> pmin2/pidx2 [row][32 groups][2].
__global__ __launch_bounds__(512, 2)
void vq_mfma(const f16* __restrict__ Ap, const f16* __restrict__ Bp,
             const float* __restrict__ cbn,
             float* __restrict__ pmin2, int* __restrict__ pidx2) {
    __shared__ __align__(16) f16 L[2][16384];   // 2 bufs x (A 16KB | B 16KB)

    const int tid  = threadIdx.x;
    const int lane = tid & 63;
    const int w    = tid >> 6;
    const int wr   = w >> 2;        // 0..1  (M half: 128 rows)
    const int wc   = w & 3;         // 0..3  (N quarter: 64 codes)
    const int l15  = lane & 15;
    const int l4   = lane >> 4;

    const int id  = blockIdx.x;
    const int swz = (id & 7) * 256 + (id >> 3);   // bijective digit swap
    const int bx  = swz & 63;                     // rows bx*256
    const int by  = swz >> 6;                     // codes by*256

    const char* Ag = (const char*)Ap + (size_t)bx * 131072;  // 16 rowtiles * 8KB
    const char* Bg = (const char*)Bp + (size_t)by * 131072;

    auto stage = [&](int vk, int b) {
        #pragma unroll
        for (int i = 0; i < 2; i++) {
            const int off = i * 8192 + tid * 16;
            const int s   = off >> 10;
            const int win = off & 1023;
            gload16(Ag + (size_t)(s * 8 + vk) * 1024 + win, (char*)&L[b][0] + off);
        }
        #pragma unroll
        for (int i = 0; i < 2; i++) {
            const int off = i * 8192 + tid * 16;
            const int s   = off >> 10;
            const int win = off & 1023;
            gload16(Bg + (size_t)(s * 8 + vk) * 1024 + win, (char*)&L[b][0] + 16384 + off);
        }
    };

    f32x4 acc[8][4];
    #pragma unroll
    for (int m = 0; m < 8; m++)
        #pragma unroll
        for (int n = 0; n < 4; n++) acc[m][n] = (f32x4){0.f, 0.f, 0.f, 0.f};

    stage(0, 0);
    int cur = 0;

    for (int vk = 0; vk < 8; vk++) {
        __syncthreads();              // drains stage(vk) + prev iter's reads
        if (vk < 7) stage(vk + 1, cur ^ 1);

        const f16* Abase = &L[cur][0]    + (wr * 8) * 512;
        const f16* Bbase = &L[cur][8192] + (wc * 4) * 512;

        f16x8 bf[4], af[8];
        #pragma unroll
        for (int n = 0; n < 4; n++) bf[n] = *(const f16x8*)(Bbase + n * 512 + lane * 8);
        #pragma unroll
        for (int mm = 0; mm < 8; mm++) af[mm] = *(const f16x8*)(Abase + mm * 512 + lane * 8);

        __builtin_amdgcn_s_setprio(1);
        #pragma unroll
        for (int mm = 0; mm < 8; mm++)
            #pragma unroll
            for (int n = 0; n < 4; n++)
                acc[mm][n] = __builtin_amdgcn_mfma_f32_16x16x32_f16(af[mm], bf[n], acc[mm][n], 0, 0, 0);
        __builtin_amdgcn_s_setprio(0);

        cur ^= 1;
    }

    // ---------- epilogue: per-row top-2 within the wave's 64-code quarter ----
    // Scratch overlays L[0] bytes 0..16383 (vk=7 read L[1]; all gloads drained
    // by vk=7's opening __syncthreads).
    float* sMin = (float*)&L[0][0];                     // [4][256][2]
    int*   sIdx = (int*)((char*)&L[0][0] + 8192);       // [4][256][2]

    #pragma unroll
    for (int m = 0; m < 8; m++) {
        float m1[4], m2[4]; int i1[4], i2[4];
        #pragma unroll
        for (int r = 0; r < 4; r++) { m1[r] = 3.4e38f; m2[r] = 3.4e38f; i1[r] = 0x7fffffff; i2[r] = 0x7fffffff; }
        #pragma unroll
        for (int n = 0; n < 4; n++) {
            const int c = by * 256 + wc * 64 + n * 16 + l15;
            const float cn = cbn[c];
            #pragma unroll
            for (int r = 0; r < 4; r++) {
                float s = cn - acc[m][n][r] * 0.03125f;
                ins2(s, c, m1[r], i1[r], m2[r], i2[r]);
            }
        }
        #pragma unroll
        for (int r = 0; r < 4; r++) {
            float a1 = m1[r], a2 = m2[r]; int b1 = i1[r], b2 = i2[r];
            #pragma unroll
            for (int o = 1; o < 16; o <<= 1) {
                float oa1 = __shfl_xor(a1, o, 64); int ob1 = __shfl_xor(b1, o, 64);
                float oa2 = __shfl_xor(a2, o, 64); int ob2 = __shfl_xor(b2, o, 64);
                if (oa1 < a1 || (oa1 == a1 && ob1 < b1)) {
                    float nm2; int ni2;
                    if (a1 < oa2 || (a1 == oa2 && b1 < ob2)) { nm2 = a1; ni2 = b1; }
                    else                                     { nm2 = oa2; ni2 = ob2; }
                    a1 = oa1; b1 = ob1; a2 = nm2; b2 = ni2;
                } else {
                    if (oa1 < a2 || (oa1 == a2 && ob1 < b2)) { a2 = oa1; b2 = ob1; }
                }
            }
            if (l15 == 0) {
                const int rloc = wr * 128 + m * 16 + l4 * 4 + r;
                sMin[(wc * 256 + rloc) * 2 + 0] = a1;
                sMin[(wc * 256 + rloc) * 2 + 1] = a2;
                sIdx[(wc * 256 + rloc) * 2 + 0] = b1;
                sIdx[(wc * 256 + rloc) * 2 + 1] = b2;
            }
        }
    }
    __syncthreads();

    if (tid < 256) {
        float m1 = 3.4e38f, m2 = 3.4e38f; int i1 = 0x7fffffff, i2 = 0x7fffffff;
        #pragma unroll
        for (int j = 0; j < 4; j++)
            #pragma unroll
            for (int k = 0; k < 2; k++) {
                float v = sMin[(j * 256 + tid) * 2 + k];
                int   iv = sIdx[(j * 256 + tid) * 2 + k];
                ins2(v, iv, m1, i1, m2, i2);
            }
        const size_t rbase = (size_t)(bx * 256 + tid) * 64 + by * 2;
        pmin2[rbase + 0] = m1; pmin2[rbase + 1] = m2;
        pidx2[rbase + 0] = i1; pidx2[rbase + 1] = i2;
    }
}

// ---------- combine: approx-min + delta-flag + exact fp32 rescore ----------
// block 256 = 4 waves, one row per wave; grid N/4.
__global__ void combine_k(const float* __restrict__ lat, const float* __restrict__ cb,
                          const float* __restrict__ cbn,
                          const float* __restrict__ pmin2, const int* __restrict__ pidx2,
                          float* __restrict__ out_q, float* __restrict__ out_idx,
                          float* __restrict__ loss_part) {
    const int tid = threadIdx.x, lane = tid & 63, wv = tid >> 6;
    const int row = blockIdx.x * 4 + wv;

    float val = pmin2[(size_t)row * 64 + lane];
    int   idv = pidx2[(size_t)row * 64 + lane];

    float g = val;
    #pragma unroll
    for (int o = 32; o; o >>= 1) g = fminf(g, __shfl_xor(g, o, 64));

    unsigned long long mask = __ballot(val <= g + DELTA);
    float4 x = *(const float4*)&lat[(size_t)row * DDIM + lane * 4];

    int idx;
    if (__popcll(mask) == 1) {
        idx = __shfl(idv, (int)__builtin_ctzll(mask), 64);
    } else {
        float bs = 3.4e38f; int bi = 0x7fffffff;
        unsigned long long mm = mask;
        while (mm) {
            int l = (int)__builtin_ctzll(mm); mm &= mm - 1;
            int cand = __shfl(idv, l, 64);
            float4 e = *(const float4*)&cb[(size_t)cand * DDIM + lane * 4];
            float d = x.x * e.x + x.y * e.y + x.z * e.z + x.w * e.w;
            #pragma unroll
            for (int o = 32; o; o >>= 1) d += __shfl_xor(d, o, 64);
            float s = cbn[cand] - 2.0f * d;
            if (s < bs || (s == bs && cand < bi)) { bs = s; bi = cand; }
        }
        idx = bi;
    }

    float4 q = *(const float4*)&cb[(size_t)idx * DDIM + lane * 4];
    *(float4*)&out_q[(size_t)row * DDIM + lane * 4] = q;
    if (lane == 0) out_idx[row] = (float)idx;

    float dx = q.x - x.x, dy = q.y - x.y, dz = q.z - x.z, dw = q.w - x.w;
    float s = dx * dx + dy * dy + dz * dz + dw * dw;
    #pragma unroll
    for (int o = 32; o; o >>= 1) s += __shfl_xor(s, o, 64);

    __shared__ float red[4];
    if (lane == 0) red[wv] = s;
    __syncthreads();
    if (tid == 0) loss_part[blockIdx.x] = red[0] + red[1] + red[2] + red[3];
}

__global__ void loss_k(const float* __restrict__ part, float* __restrict__ out_loss) {
    float s = 0.0f;
    for (int i = threadIdx.x; i < N_ROWS / 4; i += 256) s += part[i];
    #pragma unroll
    for (int m = 32; m; m >>= 1) s += __shfl_xor(s, m, 64);
    __shared__ float wsum[4];
    int lane = threadIdx.x & 63, w = threadIdx.x >> 6;
    if (lane == 0) wsum[w] = s;
    __syncthreads();
    if (threadIdx.x == 0) {
        float t = wsum[0] + wsum[1] + wsum[2] + wsum[3];
        *out_loss = (1.0f + BETA) * t / (float)((size_t)N_ROWS * DDIM);
    }
}

extern "C" void kernel_launch(void* const* d_in, const int* in_sizes, int n_in,
                              void* d_out, int out_size, void* d_ws, size_t ws_size,
                              hipStream_t stream) {
    const float* lat = (const float*)d_in[0];   // [16,32,32,256] fp32
    const float* cb  = (const float*)d_in[1];   // [8192,256] fp32

    float* ws = (float*)d_ws;
    f16*   Ap       = (f16*)ws;                          // N*256 f16   (2097152 fslots)
    f16*   Bp       = (f16*)(ws + 2097152);              // V*256 f16   (1048576 fslots)
    float* cbn      = ws + 2097152 + 1048576;            // 8192
    float* pmin2    = cbn + VCODES;                      // N*64
    int*   pidx2    = (int*)(pmin2 + (size_t)N_ROWS * 64);   // N*64
    float* losspart = (float*)(pidx2 + (size_t)N_ROWS * 64); // 4096

    float* out_q    = (float*)d_out;                     // 4194304
    float* out_loss = out_q + (size_t)N_ROWS * DDIM;     // 1
    float* out_idx  = out_loss + 1;                      // 16384 (as fp32)

    split_lat<<<N_ROWS * DDIM / 1024, 256, 0, stream>>>(lat, Ap);
    split_cb<<<VCODES * DDIM / 1024, 256, 0, stream>>>(cb, Bp);
    cbnorm_k<<<VCODES / 4, 256, 0, stream>>>(cb, cbn);

    vq_mfma<<<2048, 512, 0, stream>>>(Ap, Bp, cbn, pmin2, pidx2);

    combine_k<<<N_ROWS / 4, 256, 0, stream>>>(lat, cb, cbn, pmin2, pidx2,
                                              out_q, out_idx, losspart);
    loss_k<<<1, 256, 0, stream>>>(losspart, out_loss);
}

// Round 10
// 426.295 us; speedup vs baseline: 1.6144x; 1.6144x over previous
//
#include <hip/hip_runtime.h>

#define N_ROWS 16384
#define DDIM   256
#define VCODES 8192
#define BETA   0.25f
#define DELTA  0.02f   // rescore window; > 2x max approx error (~4e-3) w/ margin

using f16   = _Float16;
using f16x4 = __attribute__((ext_vector_type(4))) _Float16;
using f16x8 = __attribute__((ext_vector_type(8))) _Float16;
using f32x4 = __attribute__((ext_vector_type(4))) float;

typedef __attribute__((address_space(1))) const unsigned int gu32_t;
typedef __attribute__((address_space(3))) unsigned int       lu32_t;

__device__ __forceinline__ void gload16(const void* g, void* l) {
    __builtin_amdgcn_global_load_lds((gu32_t*)g, (lu32_t*)l, 16, 0, 0);
}

// ============================================================================
// Packed fragment-major layout (validated R2-R9), hi-only:
//   array[rowtile16][ktile 0..7][512 f16]  (1 KB per 16-row x 32-col subtile)
//   element (r, c) at f16 index (c>>3)*128 + r*8 + (c&7) == lane*8+j fragment
//   order for mfma_f32_16x16x32_f16.
// ============================================================================

__global__ void split_lat(const float* __restrict__ lat, f16* __restrict__ Ap) {
    int t = blockIdx.x * 256 + threadIdx.x;
    float4 x = *(const float4*)&lat[(size_t)t * 4];
    int row = t >> 6;
    int c   = (t & 63) * 4;
    f16x4 hi = {(f16)x.x, (f16)x.y, (f16)x.z, (f16)x.w};
    int kt  = c >> 5;
    int sub = ((c & 31) >> 3) * 128 + (row & 15) * 8 + (c & 7);
    size_t base = ((size_t)(row >> 4) * 8);
    *(f16x4*)&Ap[(base + kt) * 512 + sub] = hi;
}

__global__ void split_cb(const float* __restrict__ cb, f16* __restrict__ Bp) {
    int t = blockIdx.x * 256 + threadIdx.x;
    float4 e = *(const float4*)&cb[(size_t)t * 4];
    // E = 64*e keeps f16 values normal; acc = 64*x.e, score = cbn - acc/32
    f16x4 hi = {(f16)(e.x * 64.0f), (f16)(e.y * 64.0f),
                (f16)(e.z * 64.0f), (f16)(e.w * 64.0f)};
    int row = t >> 6;
    int c   = (t & 63) * 4;
    int kt  = c >> 5;
    int sub = ((c & 31) >> 3) * 128 + (row & 15) * 8 + (c & 7);
    size_t base = ((size_t)(row >> 4) * 8);
    *(f16x4*)&Bp[(base + kt) * 512 + sub] = hi;
}

__global__ void cbnorm_k(const float* __restrict__ cb, float* __restrict__ cbnorm) {
    int gtid = blockIdx.x * blockDim.x + threadIdx.x;
    int wave = gtid >> 6;
    int lane = threadIdx.x & 63;
    if (wave >= VCODES) return;
    float4 v = *(const float4*)(cb + (size_t)wave * DDIM + lane * 4);
    float s = v.x * v.x + v.y * v.y + v.z * v.z + v.w * v.w;
    #pragma unroll
    for (int m = 32; m; m >>= 1) s += __shfl_xor(s, m, 64);
    if (lane == 0) cbnorm[wave] = s;
}

// ---------- lexicographic (score, idx) top-2 insert (LDS merge only) --------
__device__ __forceinline__ void ins2(float v, int i,
                                     float& m1, int& i1, float& m2, int& i2) {
    if (v < m1 || (v == m1 && i < i1)) { m2 = m1; i2 = i1; m1 = v; i1 = i; }
    else if (v < m2 || (v == m2 && i < i2)) { m2 = v; i2 = i; }
}

// ---------- main: 256x256 tile, 8 waves (2Mx4N), 8 K-tiles, double buffer ---
// R7-proven sync: ONE __syncthreads per K-tile; stage(vk+1) issued right after
// the barrier into buf^1, drains at the NEXT __syncthreads.
// Epilogue (compact-code): lane-local top2-of-4 (VALU) -> rolled 16-lane
// double reduce (top1, then masked alternates for top2) -> LDS cross-wc merge.
__global__ __launch_bounds__(512, 2)
void vq_mfma(const f16* __restrict__ Ap, const f16* __restrict__ Bp,
             const float* __restrict__ cbn,
             float* __restrict__ pmin2, int* __restrict__ pidx2) {
    __shared__ __align__(16) f16 L[2][16384];   // 2 bufs x (A 16KB | B 16KB)

    const int tid  = threadIdx.x;
    const int lane = tid & 63;
    const int w    = tid >> 6;
    const int wr   = w >> 2;        // 0..1  (M half: 128 rows)
    const int wc   = w & 3;         // 0..3  (N quarter: 64 codes)
    const int l15  = lane & 15;
    const int l4   = lane >> 4;

    const int id  = blockIdx.x;
    const int swz = (id & 7) * 256 + (id >> 3);   // bijective digit swap
    const int bx  = swz & 63;                     // rows bx*256
    const int by  = swz >> 6;                     // codes by*256

    const char* Ag = (const char*)Ap + (size_t)bx * 131072;  // 16 rowtiles * 8KB
    const char* Bg = (const char*)Bp + (size_t)by * 131072;

    auto stage = [&](int vk, int b) {
        #pragma unroll
        for (int i = 0; i < 2; i++) {
            const int off = i * 8192 + tid * 16;
            const int s   = off >> 10;
            const int win = off & 1023;
            gload16(Ag + (size_t)(s * 8 + vk) * 1024 + win, (char*)&L[b][0] + off);
        }
        #pragma unroll
        for (int i = 0; i < 2; i++) {
            const int off = i * 8192 + tid * 16;
            const int s   = off >> 10;
            const int win = off & 1023;
            gload16(Bg + (size_t)(s * 8 + vk) * 1024 + win, (char*)&L[b][0] + 16384 + off);
        }
    };

    f32x4 acc[8][4];
    #pragma unroll
    for (int m = 0; m < 8; m++)
        #pragma unroll
        for (int n = 0; n < 4; n++) acc[m][n] = (f32x4){0.f, 0.f, 0.f, 0.f};

    stage(0, 0);
    int cur = 0;

    for (int vk = 0; vk < 8; vk++) {
        __syncthreads();              // drains stage(vk) + prev iter's reads
        if (vk < 7) stage(vk + 1, cur ^ 1);

        const f16* Abase = &L[cur][0]    + (wr * 8) * 512;
        const f16* Bbase = &L[cur][8192] + (wc * 4) * 512;

        f16x8 bf[4], af[8];
        #pragma unroll
        for (int n = 0; n < 4; n++) bf[n] = *(const f16x8*)(Bbase + n * 512 + lane * 8);
        #pragma unroll
        for (int mm = 0; mm < 8; mm++) af[mm] = *(const f16x8*)(Abase + mm * 512 + lane * 8);

        __builtin_amdgcn_s_setprio(1);
        #pragma unroll
        for (int mm = 0; mm < 8; mm++)
            #pragma unroll
            for (int n = 0; n < 4; n++)
                acc[mm][n] = __builtin_amdgcn_mfma_f32_16x16x32_f16(af[mm], bf[n], acc[mm][n], 0, 0, 0);
        __builtin_amdgcn_s_setprio(0);

        cur ^= 1;
    }

    // ---------- epilogue: per-row top-2 within the wave's 64-code quarter ----
    // Scratch overlays L[0] bytes 0..16383 (vk=7 read L[1]; all gloads drained
    // by vk=7's opening __syncthreads).
    float* sMin = (float*)&L[0][0];                     // [4][256][2]
    int*   sIdx = (int*)((char*)&L[0][0] + 8192);       // [4][256][2]

    // hoisted: the 4 codebook-norm values this lane touches (same for all m,r)
    const int cb0 = by * 256 + wc * 64 + l15;
    float cn[4];
    #pragma unroll
    for (int n = 0; n < 4; n++) cn[n] = cbn[cb0 + n * 16];

    #pragma unroll
    for (int m = 0; m < 8; m++) {
        #pragma unroll
        for (int r = 0; r < 4; r++) {
            // lane-local top-2 over the 4 scores (n = 0..3), pure VALU
            float l1 = 3.4e38f, l2 = 3.4e38f; int i1 = 0x7fffffff, i2 = 0x7fffffff;
            #pragma unroll
            for (int n = 0; n < 4; n++) {
                float s = cn[n] - acc[m][n][r] * 0.03125f;
                int   c = cb0 + n * 16;
                if (s < l1) { l2 = l1; i2 = i1; l1 = s; i1 = c; }
                else if (s < l2) { l2 = s; i2 = c; }
            }
            // 16-lane reduce #1: group top-1 (lex on idx for determinism)
            float a1 = l1; int b1 = i1;
            #pragma clang loop unroll(disable)
            for (int o = 1; o < 16; o <<= 1) {
                float t = __shfl_xor(a1, o, 64); int tb = __shfl_xor(b1, o, 64);
                if (t < a1 || (t == a1 && tb < b1)) { a1 = t; b1 = tb; }
            }
            // 16-lane reduce #2: alternates (winner lane contributes its 2nd)
            float c2 = (b1 == i1) ? l2 : l1;
            int   d2 = (b1 == i1) ? i2 : i1;
            #pragma clang loop unroll(disable)
            for (int o = 1; o < 16; o <<= 1) {
                float t = __shfl_xor(c2, o, 64); int tb = __shfl_xor(d2, o, 64);
                if (t < c2 || (t == c2 && tb < d2)) { c2 = t; d2 = tb; }
            }
            if (l15 == 0) {
                const int rloc = wr * 128 + m * 16 + l4 * 4 + r;
                sMin[(wc * 256 + rloc) * 2 + 0] = a1;
                sMin[(wc * 256 + rloc) * 2 + 1] = c2;
                sIdx[(wc * 256 + rloc) * 2 + 0] = b1;
                sIdx[(wc * 256 + rloc) * 2 + 1] = d2;
            }
        }
    }
    __syncthreads();

    if (tid < 256) {
        float m1 = 3.4e38f, m2 = 3.4e38f; int i1 = 0x7fffffff, i2 = 0x7fffffff;
        #pragma unroll
        for (int j = 0; j < 4; j++)
            #pragma unroll
            for (int k = 0; k < 2; k++) {
                float v = sMin[(j * 256 + tid) * 2 + k];
                int   iv = sIdx[(j * 256 + tid) * 2 + k];
                ins2(v, iv, m1, i1, m2, i2);
            }
        const size_t rbase = (size_t)(bx * 256 + tid) * 64 + by * 2;
        pmin2[rbase + 0] = m1; pmin2[rbase + 1] = m2;
        pidx2[rbase + 0] = i1; pidx2[rbase + 1] = i2;
    }
}

// ---------- combine: approx-min + delta-flag + exact fp32 rescore ----------
// block 256 = 4 waves, one row per wave; grid N/4.
__global__ void combine_k(const float* __restrict__ lat, const float* __restrict__ cb,
                          const float* __restrict__ cbn,
                          const float* __restrict__ pmin2, const int* __restrict__ pidx2,
                          float* __restrict__ out_q, float* __restrict__ out_idx,
                          float* __restrict__ loss_part) {
    const int tid = threadIdx.x, lane = tid & 63, wv = tid >> 6;
    const int row = blockIdx.x * 4 + wv;

    float val = pmin2[(size_t)row * 64 + lane];
    int   idv = pidx2[(size_t)row * 64 + lane];

    float g = val;
    #pragma unroll
    for (int o = 32; o; o >>= 1) g = fminf(g, __shfl_xor(g, o, 64));

    unsigned long long mask = __ballot(val <= g + DELTA);
    float4 x = *(const float4*)&lat[(size_t)row * DDIM + lane * 4];

    int idx;
    if (__popcll(mask) == 1) {
        idx = __shfl(idv, (int)__builtin_ctzll(mask), 64);
    } else {
        float bs = 3.4e38f; int bi = 0x7fffffff;
        unsigned long long mm = mask;
        while (mm) {
            int l = (int)__builtin_ctzll(mm); mm &= mm - 1;
            int cand = __shfl(idv, l, 64);
            float4 e = *(const float4*)&cb[(size_t)cand * DDIM + lane * 4];
            float d = x.x * e.x + x.y * e.y + x.z * e.z + x.w * e.w;
            #pragma unroll
            for (int o = 32; o; o >>= 1) d += __shfl_xor(d, o, 64);
            float s = cbn[cand] - 2.0f * d;
            if (s < bs || (s == bs && cand < bi)) { bs = s; bi = cand; }
        }
        idx = bi;
    }

    float4 q = *(const float4*)&cb[(size_t)idx * DDIM + lane * 4];
    *(float4*)&out_q[(size_t)row * DDIM + lane * 4] = q;
    if (lane == 0) out_idx[row] = (float)idx;

    float dx = q.x - x.x, dy = q.y - x.y, dz = q.z - x.z, dw = q.w - x.w;
    float s = dx * dx + dy * dy + dz * dz + dw * dw;
    #pragma unroll
    for (int o = 32; o; o >>= 1) s += __shfl_xor(s, o, 64);

    __shared__ float red[4];
    if (lane == 0) red[wv] = s;
    __syncthreads();
    if (tid == 0) loss_part[blockIdx.x] = red[0] + red[1] + red[2] + red[3];
}

__global__ void loss_k(const float* __restrict__ part, float* __restrict__ out_loss) {
    float s = 0.0f;
    for (int i = threadIdx.x; i < N_ROWS / 4; i += 256) s += part[i];
    #pragma unroll
    for (int m = 32; m; m >>= 1) s += __shfl_xor(s, m, 64);
    __shared__ float wsum[4];
    int lane = threadIdx.x & 63, w = threadIdx.x >> 6;
    if (lane == 0) wsum[w] = s;
    __syncthreads();
    if (threadIdx.x == 0) {
        float t = wsum[0] + wsum[1] + wsum[2] + wsum[3];
        *out_loss = (1.0f + BETA) * t / (float)((size_t)N_ROWS * DDIM);
    }
}

extern "C" void kernel_launch(void* const* d_in, const int* in_sizes, int n_in,
                              void* d_out, int out_size, void* d_ws, size_t ws_size,
                              hipStream_t stream) {
    const float* lat = (const float*)d_in[0];   // [16,32,32,256] fp32
    const float* cb  = (const float*)d_in[1];   // [8192,256] fp32

    float* ws = (float*)d_ws;
    f16*   Ap       = (f16*)ws;                          // N*256 f16
    f16*   Bp       = (f16*)(ws + 2097152);              // V*256 f16
    float* cbn      = ws + 2097152 + 1048576;            // 8192
    float* pmin2    = cbn + VCODES;                      // N*64
    int*   pidx2    = (int*)(pmin2 + (size_t)N_ROWS * 64);   // N*64
    float* losspart = (float*)(pidx2 + (size_t)N_ROWS * 64); // 4096

    float* out_q    = (float*)d_out;                     // 4194304
    float* out_loss = out_q + (size_t)N_ROWS * DDIM;     // 1
    float* out_idx  = out_loss + 1;                      // 16384 (as fp32)

    split_lat<<<N_ROWS * DDIM / 1024, 256, 0, stream>>>(lat, Ap);
    split_cb<<<VCODES * DDIM / 1024, 256, 0, stream>>>(cb, Bp);
    cbnorm_k<<<VCODES / 4, 256, 0, stream>>>(cb, cbn);

    vq_mfma<<<2048, 512, 0, stream>>>(Ap, Bp, cbn, pmin2, pidx2);

    combine_k<<<N_ROWS / 4, 256, 0, stream>>>(lat, cb, cbn, pmin2, pidx2,
                                              out_q, out_idx, losspart);
    loss_k<<<1, 256, 0, stream>>>(losspart, out_loss);
}